// Round 8
// baseline (53.695 us; speedup 1.0000x reference)
//
#include <hip/hip_runtime.h>

// Top1Gate via bf16x3-split MFMA GEMM, v8.
// logits = x @ W^T [16384,64]; idx = argmax; scores = max; mask = one-hot.
// Output flat (float32): [idx 16384][scores 16384][mask 16384*64]
//
// v8 vs v6: BM 32->16, grid 1024 -> 4 blocks/CU, 4 waves/SIMD (occupancy
// was the untested lever; R7 proved wconv pre-pass must stay for coalescing).
// Chunk = 16 rows x 128 k; 16 chunks; per-chunk B loads (no pairing, still
// read-once per block); full 16-way de-phase; re-derived vmcnt schedule.

typedef float  f32x4  __attribute__((ext_vector_type(4)));
typedef short  bf16x8 __attribute__((ext_vector_type(8)));

constexpr int BATCH = 16384;
constexpr int DM    = 2048;
constexpr int NE    = 64;
constexpr int BM    = 16;          // rows per block
constexpr int NT    = 256;         // 4 waves = 4 k-quarters
constexpr int NCH   = 16;          // chunks of 16 rows x 128 k (8 KB)

// wf layout (d_ws, ushort): [ks=64][term=2][tile=4][lane=64][j=8]
// value = w_term[expert = tile*16 + (lane&15)][k = ks*32 + (lane>>4)*8 + j]

__device__ __forceinline__ void split_bf16(float f, unsigned short& hi, unsigned short& lo) {
    unsigned u  = __float_as_uint(f);
    unsigned h  = (u + 0x8000u) >> 16;           // round-half-up to bf16
    float    hf = __uint_as_float(h << 16);
    unsigned l  = __float_as_uint(f - hf) >> 16; // truncate residual
    hi = (unsigned short)h;
    lo = (unsigned short)l;
}

__global__ __launch_bounds__(256, 1)
void wconv_kernel(const float* __restrict__ w, unsigned short* __restrict__ wf) {
    int i  = blockIdx.x * 256 + threadIdx.x;     // 0..131071
    int ks = i >> 11;
    int n  = (i >> 9) & 3;
    int l  = (i >> 3) & 63;
    int j  = i & 7;
    int e  = n * 16 + (l & 15);
    int k  = ks * 32 + (l >> 4) * 8 + j;
    float v = w[(size_t)e * DM + k];
    unsigned short hi, lo;
    split_bf16(v, hi, lo);
    int base = ((ks * 2 + 0) * 4 + n) * 512 + l * 8 + j;
    wf[base]        = hi;               // term 0
    wf[base + 2048] = lo;               // term 1
}

struct BSet { bf16x8 v[8]; };   // [term=2(hi,lo)][tile=4] for one 32-k step

__global__ __launch_bounds__(NT, 4)
void gate_kernel(const float* __restrict__ x,
                 const unsigned short* __restrict__ wf,
                 float* __restrict__ out) {
    __shared__ alignas(16) float xs[4][16 * 32 * 4];   // 4-slot ring x 8 KB
    __shared__ float lg[BM][NE + 1];                   // stride 65
    __shared__ int   s_idx[BM];

    const int t     = threadIdx.x;
    const int lane  = t & 63;
    const int q     = t >> 6;                // k-quarter 0..3
    const int row0  = blockIdx.x * BM;
    const int phase = blockIdx.x & 15;       // full 16-way de-phase

    f32x4 acc[4];
    #pragma unroll
    for (int n = 0; n < 4; ++n) acc[n] = (f32x4){0.f, 0.f, 0.f, 0.f};

    auto kbOf = [&](int c) { return (c + phase) & 15; };

    // stage chunk c into ring slot b: 16 rows x 128 k = 512 f4, 2/thread
    auto stage_x = [&](int c, int b) {
        const float* xg = x + (size_t)row0 * DM + kbOf(c) * 128;
        #pragma unroll
        for (int i = 0; i < 2; ++i) {
            int d    = i * NT + t;            // 0..511 linear dest f4 slot
            int r    = d >> 5;                // row 0..15
            int sdst = d & 31;
            int ssrc = sdst ^ ((r & 7) << 2); // pre-swizzled source (linear LDS dest)
            __builtin_amdgcn_global_load_lds(
                (const __attribute__((address_space(1))) void*)(xg + (size_t)r * DM + ssrc * 4),
                (__attribute__((address_space(3))) void*)(&xs[b][d * 4]),
                16, 0, 0);
        }
    };

    // load this wave's B fragments for chunk c (k-step = quarter q): 8 KB/wave,
    // fully coalesced (lane*16B contiguous)
    auto load_b = [&](int c, BSet& B) {
        int ks = kbOf(c) * 4 + q;
        const unsigned short* wg = wf + (size_t)ks * 4096 + lane * 8;
        #pragma unroll
        for (int f = 0; f < 8; ++f)           // f = term*4 + tile
            B.v[f] = *(const bf16x8*)(wg + (size_t)f * 512);
    };

    // compute chunk in ring slot b, this wave's 32-k quarter
    auto compute = [&](int b, const BSet& B) {
        const int rA = lane & 15;
        const int s0 = q * 8 + ((lane >> 4) << 1);
        const int xr = (rA & 7) << 2;
        f32x4 a0 = *(const f32x4*)&xs[b][(rA * 32 + ((s0 + 0) ^ xr)) * 4];
        f32x4 a1 = *(const f32x4*)&xs[b][(rA * 32 + ((s0 + 1) ^ xr)) * 4];
        bf16x8 ahi, alo;
        #pragma unroll
        for (int j = 0; j < 8; ++j) {
            float f = (j < 4) ? a0[j] : a1[j - 4];
            unsigned short h, l;
            split_bf16(f, h, l);
            ahi[j] = (short)h;
            alo[j] = (short)l;
        }
        #pragma unroll
        for (int n = 0; n < 4; ++n) {
            acc[n] = __builtin_amdgcn_mfma_f32_16x16x32_bf16(ahi, B.v[0 + n], acc[n], 0, 0, 0);
            acc[n] = __builtin_amdgcn_mfma_f32_16x16x32_bf16(ahi, B.v[4 + n], acc[n], 0, 0, 0);
            acc[n] = __builtin_amdgcn_mfma_f32_16x16x32_bf16(alo, B.v[0 + n], acc[n], 0, 0, 0);
        }
    };

    BSet BA, BB;

    // prologue: B(0):8, X0:2, X1:2, X2:2 = 14 outstanding
    load_b(0, BA);
    stage_x(0, 0);
    stage_x(1, 1);
    stage_x(2, 2);

    // steady state iter c: issue B(c+1):8, X(c+3):2; outstanding 22 =
    // [X(c+1):2, B(c):8, X(c+2):2, B(c+1):8, X(c+3):2] -> wait(12) drains
    // X(c+1), B(c). compute(c) (X(c) drained at iter c-1, before barrier).
    #pragma unroll 1
    for (int c = 0; c < 12; c += 2) {
        load_b(c + 1, BB);
        stage_x(c + 3, (c + 3) & 3);
        asm volatile("s_waitcnt vmcnt(12)" ::: "memory");
        __builtin_amdgcn_sched_barrier(0);
        compute(c & 3, BA);
        __builtin_amdgcn_s_barrier();

        load_b(c + 2, BA);
        stage_x(c + 4, (c + 4) & 3);
        asm volatile("s_waitcnt vmcnt(12)" ::: "memory");
        __builtin_amdgcn_sched_barrier(0);
        compute((c + 1) & 3, BB);
        __builtin_amdgcn_s_barrier();
    }
    // c=12: issue B(13), X(15). outstanding [X13:2,B12:8,X14:2,B13:8,X15:2]=22
    load_b(13, BB);
    stage_x(15, 3);
    asm volatile("s_waitcnt vmcnt(12)" ::: "memory");   // drain X13, B12
    __builtin_amdgcn_sched_barrier(0);
    compute(0, BA);
    __builtin_amdgcn_s_barrier();
    // c=13: issue B(14). outstanding [X14:2,B13:8,X15:2,B14:8]=20
    load_b(14, BA);
    asm volatile("s_waitcnt vmcnt(10)" ::: "memory");   // drain X14, B13
    __builtin_amdgcn_sched_barrier(0);
    compute(1, BB);
    __builtin_amdgcn_s_barrier();
    // c=14: issue B(15). outstanding [X15:2,B14:8,B15:8]=18
    load_b(15, BB);
    asm volatile("s_waitcnt vmcnt(8)" ::: "memory");    // drain X15, B14
    __builtin_amdgcn_sched_barrier(0);
    compute(2, BA);
    __builtin_amdgcn_s_barrier();
    // c=15: drain all
    asm volatile("s_waitcnt vmcnt(0)" ::: "memory");
    __builtin_amdgcn_sched_barrier(0);
    compute(3, BB);
    __syncthreads();

    // 4-way k-quarter reduce into lg (deterministic serial order)
    // C/D layout: row_local = (lane>>4)*4 + j, col = n*16 + (lane&15)
    const int rb = (lane >> 4) << 2;
    const int cb = lane & 15;
    if (q == 0) {
        #pragma unroll
        for (int n = 0; n < 4; ++n)
            #pragma unroll
            for (int j = 0; j < 4; ++j)
                lg[rb + j][n * 16 + cb] = acc[n][j];
    }
    __syncthreads();
    if (q == 1) {
        #pragma unroll
        for (int n = 0; n < 4; ++n)
            #pragma unroll
            for (int j = 0; j < 4; ++j)
                lg[rb + j][n * 16 + cb] += acc[n][j];
    }
    __syncthreads();
    if (q == 2) {
        #pragma unroll
        for (int n = 0; n < 4; ++n)
            #pragma unroll
            for (int j = 0; j < 4; ++j)
                lg[rb + j][n * 16 + cb] += acc[n][j];
    }
    __syncthreads();
    if (q == 3) {
        #pragma unroll
        for (int n = 0; n < 4; ++n)
            #pragma unroll
            for (int j = 0; j < 4; ++j)
                lg[rb + j][n * 16 + cb] += acc[n][j];
    }
    __syncthreads();

    if (t < BM) {
        float m  = lg[t][0];
        int   mi = 0;
        #pragma unroll
        for (int e = 1; e < NE; ++e) {
            float v = lg[t][e];
            if (v > m) { m = v; mi = e; }
        }
        s_idx[t] = mi;
        out[row0 + t]         = (float)mi;
        out[BATCH + row0 + t] = m;
    }
    __syncthreads();

    // one-hot mask: 16 rows x 64 = 1024 floats; 1 f32x4/thread, coalesced
    float* mask = out + 2 * (size_t)BATCH;
    int r  = t >> 4;
    int c0 = (t & 15) * 4;
    int mi = s_idx[r];
    f32x4 v;
    #pragma unroll
    for (int j = 0; j < 4; ++j) v[j] = (c0 + j == mi) ? 1.0f : 0.0f;
    *(f32x4*)&mask[(size_t)(row0 + r) * NE + c0] = v;
}

extern "C" void kernel_launch(void* const* d_in, const int* in_sizes, int n_in,
                              void* d_out, int out_size, void* d_ws, size_t ws_size,
                              hipStream_t stream) {
    const float* x = (const float*)d_in[0];
    const float* w = (const float*)d_in[1];
    float* out     = (float*)d_out;
    unsigned short* wf = (unsigned short*)d_ws;   // 512 KB

    wconv_kernel<<<dim3(512), dim3(256), 0, stream>>>(w, wf);
    gate_kernel<<<dim3(BATCH / BM), dim3(NT), 0, stream>>>(x, wf, out);
}

// Round 9
// 38.626 us; speedup vs baseline: 1.3901x; 1.3901x over previous
//
#include <hip/hip_runtime.h>

// Top1Gate via bf16x3-split MFMA GEMM, v9  (= v6 + deeper prefetch).
// logits = x @ W^T [16384,64]; idx = argmax; scores = max; mask = one-hot.
// Output flat (float32): [idx 16384][scores 16384][mask 16384*64]
//
// v9 vs v6: B prefetched 2 kblks ahead (3 rotating BSets, 96 VGPR) and x 4
// chunks ahead (8-slot LDS ring). Uniform vmcnt(24) steady state -> 3-4
// x-chunks (48-64 KB/CU) stay in flight after each wait, vs v6's 2 (B was
// issued 1 iter ahead; draining it collapsed x depth). Barrier sits between
// wait and compute (drain-through-X(c) lands the chunk consumed this iter).
// v8 lesson: launch_bounds(256,2) kept (cap 256 VGPR; (256,4) spilled).

typedef float  f32x4  __attribute__((ext_vector_type(4)));
typedef short  bf16x8 __attribute__((ext_vector_type(8)));

constexpr int BATCH = 16384;
constexpr int DM    = 2048;
constexpr int NE    = 64;
constexpr int BM    = 32;          // rows per block
constexpr int NT    = 256;         // 4 waves = 4 k-quarters
// chunk = 16 rows x 128 k = 8 KB; 32 chunks: c -> (h = c&1, kblk pair p = c>>1)

// wf layout (d_ws, ushort): [ks=64][term=2][tile=4][lane=64][j=8]
// value = w_term[expert = tile*16 + (lane&15)][k = ks*32 + (lane>>4)*8 + j]

__device__ __forceinline__ void split_bf16(float f, unsigned short& hi, unsigned short& lo) {
    unsigned u  = __float_as_uint(f);
    unsigned h  = (u + 0x8000u) >> 16;           // round-half-up to bf16
    float    hf = __uint_as_float(h << 16);
    unsigned l  = __float_as_uint(f - hf) >> 16; // truncate residual
    hi = (unsigned short)h;
    lo = (unsigned short)l;
}

__global__ __launch_bounds__(256, 1)
void wconv_kernel(const float* __restrict__ w, unsigned short* __restrict__ wf) {
    int i  = blockIdx.x * 256 + threadIdx.x;     // 0..131071
    int ks = i >> 11;
    int n  = (i >> 9) & 3;
    int l  = (i >> 3) & 63;
    int j  = i & 7;
    int e  = n * 16 + (l & 15);
    int k  = ks * 32 + (l >> 4) * 8 + j;
    float v = w[(size_t)e * DM + k];
    unsigned short hi, lo;
    split_bf16(v, hi, lo);
    int base = ((ks * 2 + 0) * 4 + n) * 512 + l * 8 + j;
    wf[base]        = hi;               // term 0
    wf[base + 2048] = lo;               // term 1
}

struct BSet { bf16x8 v[8]; };   // [term=2(hi,lo)][tile=4] for one 32-k step

#define WAITN(N) do { asm volatile("s_waitcnt vmcnt(" #N ")" ::: "memory"); \
                      __builtin_amdgcn_sched_barrier(0); \
                      __builtin_amdgcn_s_barrier(); \
                      __builtin_amdgcn_sched_barrier(0); } while (0)

__global__ __launch_bounds__(NT, 2)
void gate_kernel(const float* __restrict__ x,
                 const unsigned short* __restrict__ wf,
                 float* __restrict__ out) {
    __shared__ alignas(16) float xs[8][16 * 32 * 4];   // 8-slot ring x 8 KB = 64 KB
    __shared__ float lg[BM][NE + 1];                   // stride 65
    __shared__ int   s_idx[BM];

    const int t    = threadIdx.x;
    const int lane = t & 63;
    const int q    = t >> 6;                // k-quarter 0..3
    const int row0 = blockIdx.x * BM;
    const int pph  = blockIdx.x & 15;       // de-phase (pair granularity)

    f32x4 acc[2][4];
    #pragma unroll
    for (int h = 0; h < 2; ++h)
        #pragma unroll
        for (int n = 0; n < 4; ++n) acc[h][n] = (f32x4){0.f, 0.f, 0.f, 0.f};

    auto pb = [&](int p) { return (p + pph) & 15; };   // actual kblk of pair p

    // stage chunk c (h=c&1, kblk pb(c>>1)) into ring slot c&7: 512 f4, 2/thread
    auto stage_x = [&](int c) {
        const int h = c & 1;
        const float* xg = x + (size_t)(row0 + h * 16) * DM + pb(c >> 1) * 128;
        float* dst = &xs[c & 7][0];
        #pragma unroll
        for (int i = 0; i < 2; ++i) {
            int d    = i * NT + t;            // 0..511 linear dest f4 slot
            int r    = d >> 5;                // row 0..15
            int sdst = d & 31;
            int ssrc = sdst ^ ((r & 7) << 2); // pre-swizzled source (linear LDS dest)
            __builtin_amdgcn_global_load_lds(
                (const __attribute__((address_space(1))) void*)(xg + (size_t)r * DM + ssrc * 4),
                (__attribute__((address_space(3))) void*)(dst + d * 4),
                16, 0, 0);
        }
    };

    // load this wave's B fragments for pair p (k-step = quarter q): coalesced L2
    auto load_b = [&](int p, BSet& B) {
        int ks = pb(p) * 4 + q;
        const unsigned short* wg = wf + (size_t)ks * 4096 + lane * 8;
        #pragma unroll
        for (int f = 0; f < 8; ++f)           // f = term*4 + tile
            B.v[f] = *(const bf16x8*)(wg + (size_t)f * 512);
    };

    // compute chunk c (slot c&7, row-half hh literal), this wave's 32-k quarter
    auto compute = [&](int c, int hh, const BSet& B) {
        const float* src = &xs[c & 7][0];
        const int rA = lane & 15;
        const int s0 = q * 8 + ((lane >> 4) << 1);
        const int xr = (rA & 7) << 2;
        f32x4 a0 = *(const f32x4*)(src + (rA * 32 + ((s0 + 0) ^ xr)) * 4);
        f32x4 a1 = *(const f32x4*)(src + (rA * 32 + ((s0 + 1) ^ xr)) * 4);
        bf16x8 ahi, alo;
        #pragma unroll
        for (int j = 0; j < 8; ++j) {
            float f = (j < 4) ? a0[j] : a1[j - 4];
            unsigned short h, l;
            split_bf16(f, h, l);
            ahi[j] = (short)h;
            alo[j] = (short)l;
        }
        #pragma unroll
        for (int n = 0; n < 4; ++n) {
            acc[hh][n] = __builtin_amdgcn_mfma_f32_16x16x32_bf16(ahi, B.v[0 + n], acc[hh][n], 0, 0, 0);
            acc[hh][n] = __builtin_amdgcn_mfma_f32_16x16x32_bf16(ahi, B.v[4 + n], acc[hh][n], 0, 0, 0);
            acc[hh][n] = __builtin_amdgcn_mfma_f32_16x16x32_bf16(alo, B.v[0 + n], acc[hh][n], 0, 0, 0);
        }
    };

    BSet S0, S1, S2;

    // prologue queue (oldest->newest): B0:8, X0:2, X1:2, B1:8, X2:2, X3:2 = 24
    load_b(0, S0);
    stage_x(0);
    stage_x(1);
    load_b(1, S1);
    stage_x(2);
    stage_x(3);

    // steady state (iters c=0..27): even c issues B(c/2+2), every c issues
    // X(c+4); wait vmcnt(24) drains exactly through X(c) (and B(c/2), issued
    // just before it 4 iters earlier). Post-wait in flight: 3-4 x-chunks +
    // 1-2 B-sets. Pair p uses S[p%3], loads into S[(p+2)%3].
    #pragma unroll 1
    for (int p = 0; p < 12; p += 3) {
        const int c = 2 * p;
        // pair p (uses S0, loads B(p+2)->S2)
        load_b(p + 2, S2);
        stage_x(c + 4);
        WAITN(24);
        compute(c + 0, 0, S0);
        stage_x(c + 5);
        WAITN(24);
        compute(c + 1, 1, S0);
        // pair p+1 (uses S1, loads B(p+3)->S0)
        load_b(p + 3, S0);
        stage_x(c + 6);
        WAITN(24);
        compute(c + 2, 0, S1);
        stage_x(c + 7);
        WAITN(24);
        compute(c + 3, 1, S1);
        // pair p+2 (uses S2, loads B(p+4)->S1)
        load_b(p + 4, S1);
        stage_x(c + 8);
        WAITN(24);
        compute(c + 4, 0, S2);
        stage_x(c + 9);
        WAITN(24);
        compute(c + 5, 1, S2);
    }
    // pair 12 (uses S0, loads B14->S2)
    load_b(14, S2);
    stage_x(28);
    WAITN(24);
    compute(24, 0, S0);
    stage_x(29);
    WAITN(24);
    compute(25, 1, S0);
    // pair 13 (uses S1, loads B15->S0)
    load_b(15, S0);
    stage_x(30);
    WAITN(24);
    compute(26, 0, S1);
    stage_x(31);
    WAITN(24);
    compute(27, 1, S1);
    // tail pair 14 (S2): queue = B14,X28,X29,B15,X30,X31 = 24
    WAITN(14);                 // drain B14+X28
    compute(28, 0, S2);
    WAITN(12);                 // drain X29
    compute(29, 1, S2);
    // tail pair 15 (S0)
    WAITN(2);                  // drain B15+X30
    compute(30, 0, S0);
    WAITN(0);                  // drain X31
    compute(31, 1, S0);
    __syncthreads();

    // 4-way k-quarter reduce into lg (deterministic serial order)
    // C/D layout: row_local = (lane>>4)*4 + j, col = n*16 + (lane&15)
    const int rb = (lane >> 4) << 2;
    const int cb = lane & 15;
    if (q == 0) {
        #pragma unroll
        for (int h = 0; h < 2; ++h)
            #pragma unroll
            for (int n = 0; n < 4; ++n)
                #pragma unroll
                for (int j = 0; j < 4; ++j)
                    lg[h * 16 + rb + j][n * 16 + cb] = acc[h][n][j];
    }
    __syncthreads();
    if (q == 1) {
        #pragma unroll
        for (int h = 0; h < 2; ++h)
            #pragma unroll
            for (int n = 0; n < 4; ++n)
                #pragma unroll
                for (int j = 0; j < 4; ++j)
                    lg[h * 16 + rb + j][n * 16 + cb] += acc[h][n][j];
    }
    __syncthreads();
    if (q == 2) {
        #pragma unroll
        for (int h = 0; h < 2; ++h)
            #pragma unroll
            for (int n = 0; n < 4; ++n)
                #pragma unroll
                for (int j = 0; j < 4; ++j)
                    lg[h * 16 + rb + j][n * 16 + cb] += acc[h][n][j];
    }
    __syncthreads();
    if (q == 3) {
        #pragma unroll
        for (int h = 0; h < 2; ++h)
            #pragma unroll
            for (int n = 0; n < 4; ++n)
                #pragma unroll
                for (int j = 0; j < 4; ++j)
                    lg[h * 16 + rb + j][n * 16 + cb] += acc[h][n][j];
    }
    __syncthreads();

    if (t < BM) {
        float m  = lg[t][0];
        int   mi = 0;
        #pragma unroll
        for (int e = 1; e < NE; ++e) {
            float v = lg[t][e];
            if (v > m) { m = v; mi = e; }
        }
        s_idx[t] = mi;
        out[row0 + t]         = (float)mi;
        out[BATCH + row0 + t] = m;
    }
    __syncthreads();

    // one-hot mask: 32 rows x 64 = 2048 floats; 8/thread, coalesced f32x4
    float* mask = out + 2 * (size_t)BATCH;
    int r  = t >> 3;
    int c0 = (t & 7) * 8;
    int mi = s_idx[r];
    #pragma unroll
    for (int i = 0; i < 2; ++i) {
        f32x4 v;
        #pragma unroll
        for (int j = 0; j < 4; ++j) v[j] = (c0 + i * 4 + j == mi) ? 1.0f : 0.0f;
        *(f32x4*)&mask[(size_t)(row0 + r) * NE + c0 + i * 4] = v;
    }
}

extern "C" void kernel_launch(void* const* d_in, const int* in_sizes, int n_in,
                              void* d_out, int out_size, void* d_ws, size_t ws_size,
                              hipStream_t stream) {
    const float* x = (const float*)d_in[0];
    const float* w = (const float*)d_in[1];
    float* out     = (float*)d_out;
    unsigned short* wf = (unsigned short*)d_ws;   // 512 KB

    wconv_kernel<<<dim3(512), dim3(256), 0, stream>>>(w, wf);
    gate_kernel<<<dim3(BATCH / BM), dim3(NT), 0, stream>>>(x, wf, out);
}